// Round 9
// baseline (102894.397 us; speedup 1.0000x reference)
//
#include <hip/hip_runtime.h>
#include <cstddef>

#define B_DIM 32
#define T_DIM 1000
#define I_DIM 3
#define R_DIM 2048
#define O_DIM 3
#define NBLK 512
#define ROWS 4          // reservoir rows per block
#define NTHR 512        // 8 waves: waves 0-3 = k-half 0, waves 4-7 = k-half 1
#define KCH 128         // k per chunk (lane*2 within chunk)
#define NCH 8           // chunks per half (8*128 = 1024)

// Persistent kernel, round 9.
// vs round 7 (18.5ms, 2 waves/SIMD, VALUBusy 20% = latency-starved) and
// round 8 (23.7ms REGRESSION: 1024-thr block got VGPR capped to 64 ->
// spill -> 50GB scratch traffic):
//   - occupancy doubled the spill-free way: 512 blocks x 512 threads
//     (2 blocks/CU, 4 waves/SIMD), per-thread tile HALVED to acc[32]
//     (4 rows x 8 batches) so pressure ~110 VGPR < 128 cap.
//   - launch_bounds(512,4) pins the 128-VGPR budget explicitly.
//   - butterfly: 5 steps (m=16..1) + cross-half shfl_xor(32);
//     lanes<32 own outputs o=lane (j=o>>2, r=o&3).
//   - barrier/sc1-ordering/readout structure unchanged (verified r5-r8).
__global__ __launch_bounds__(NTHR, 4) void esn_persist(
    const float* __restrict__ x,      // [B][T][I]
    const float* __restrict__ Win,    // [R][I]
    const float* __restrict__ Wres,   // [R][R]
    const float* __restrict__ Wout,   // [O][R]
    const float* __restrict__ noise,  // [B][R]
    float* __restrict__ states,       // [B][T][R]
    float* __restrict__ out,          // [B][O]
    int* __restrict__ flags)          // [NBLK] in ws (poison 0xAA = negative)
{
  __shared__ float cross[4][32];      // k-half combine (512 B)

  const int tid   = threadIdx.x;
  const int blk   = blockIdx.x;
  const int r0    = blk * ROWS;
  const int h     = tid >> 8;         // k-half 0/1
  const int wv    = tid >> 6;         // wave 0..7
  const int wv4   = wv & 3;           // batch-group
  const int lane  = tid & 63;
  const int bbase = wv4 * 8;

  // output mapping (after butterfly): lane L<32 owns o=L: j=o>>2, r=o&3
  const int ob  = bbase + ((lane & 31) >> 2);
  const int orr = r0 + (lane & 3);
  const bool owner = (h == 0) && (lane < 32);

  // t-invariant ext-term pieces (owner lanes produce outputs)
  float w0 = 0.f, w1 = 0.f, w2 = 0.f, nz = 0.f;
  if (owner) {
    w0 = Win[orr * I_DIM + 0];
    w1 = Win[orr * I_DIM + 1];
    w2 = Win[orr * I_DIM + 2];
    nz = noise[(size_t)ob * R_DIM + orr];
  }

  // per-lane k base within this half; per-row/batch base pointers
  const int klb = h * 1024 + lane * 2;
  const float* wp[ROWS];
  const float* sp0[8];
#pragma unroll
  for (int r = 0; r < ROWS; ++r) wp[r] = Wres + (size_t)(r0 + r) * R_DIM + klb;
#pragma unroll
  for (int j = 0; j < 8; ++j)
    sp0[j] = states + (size_t)(bbase + j) * T_DIM * R_DIM + klb;

#define LOADC(kc, SF, WF)                                                      \
  {                                                                            \
    _Pragma("unroll")                                                          \
    for (int j = 0; j < 8; ++j)                                                \
      SF[j] = *(const float2*)(sp0[j] + soff + (kc) * KCH);                    \
    _Pragma("unroll")                                                          \
    for (int r = 0; r < ROWS; ++r)                                             \
      WF[r] = *(const float2*)(wp[r] + (kc) * KCH);                            \
  }

#define FMAC(SF, WF)                                                           \
  {                                                                            \
    _Pragma("unroll")                                                          \
    for (int j = 0; j < 8; ++j) {                                              \
      _Pragma("unroll")                                                        \
      for (int r = 0; r < ROWS; ++r)                                           \
        acc[j * ROWS + r] += WF[r].x * SF[j].x + WF[r].y * SF[j].y;            \
    }                                                                          \
  }

#pragma unroll 1
  for (int t = 0; t < T_DIM; ++t) {
    // per-step input loads issued early (latency hides under the k-loop)
    float x0 = 0.f, x1 = 0.f, x2 = 0.f;
    if (owner) {
      const float* xp = &x[((size_t)ob * T_DIM + t) * I_DIM];
      x0 = xp[0]; x1 = xp[1]; x2 = xp[2];
    }

    float acc[32];
#pragma unroll
    for (int i = 0; i < 32; ++i) acc[i] = 0.f;

    if (t > 0) {
      const size_t soff = (size_t)(t - 1) * R_DIM;
      float2 sA[8], wA[ROWS], sB[8], wB[ROWS];
      LOADC(0, sA, wA);
#pragma unroll
      for (int kc = 0; kc < NCH; kc += 2) {
        LOADC(kc + 1, sB, wB);              // prefetch odd chunk
        FMAC(sA, wA);                       // compute even chunk
        if (kc + 2 < NCH) LOADC(kc + 2, sA, wA);
        FMAC(sB, wB);                       // compute odd chunk
      }
    }

    // ---- in-place keep-half butterfly over lane bits 4..0:
    // acc[0] = partial of output o=(lane&31) summed over lanes w/ same bit5
#pragma unroll
    for (int m = 16; m >= 1; m >>= 1) {
#pragma unroll
      for (int i = 0; i < m; ++i) {
        const bool hh = (lane & m) != 0;
        const float mine = hh ? acc[i] : acc[i + m];
        const float keep = hh ? acc[i + m] : acc[i];
        acc[i] = keep + __shfl_xor(mine, m, 64);
      }
    }
    // cross-half-wave combine: full sum over all 64 lanes
    acc[0] += __shfl_xor(acc[0], 32, 64);

    // ---- combine k-halves, activation, sc1 store (LLC-visible)
    if (h == 1 && lane < 32) cross[wv4][lane] = acc[0];
    __syncthreads();
    if (owner) {
      const float val =
          tanhf(x0 * w0 + x1 * w1 + x2 * w2 + nz + acc[0] + cross[wv4][lane]);
      __hip_atomic_store(&states[((size_t)ob * T_DIM + t) * R_DIM + orr], val,
                         __ATOMIC_RELAXED, __HIP_MEMORY_SCOPE_AGENT);
    }
    // barrier's built-in s_waitcnt vmcnt(0) retires every wave's sc1 stores
    // at the LLC before any wave proceeds -> release ordering without wbl2.
    __syncthreads();

    // ---- grid barrier: RELAXED flag release + spin on all 512 flags
    if (tid == 0)
      __hip_atomic_store(&flags[blk], t + 1, __ATOMIC_RELAXED,
                         __HIP_MEMORY_SCOPE_AGENT);
    if (wv == 0 && (t + 1 < T_DIM || blk == 0)) {
      const int target = t + 1;
      int guard = 0;
      for (;;) {
        bool ok = true;
#pragma unroll
        for (int j = 0; j < NBLK / 64; ++j) {
          const int v = __hip_atomic_load(&flags[lane + j * 64],
                                          __ATOMIC_RELAXED,
                                          __HIP_MEMORY_SCOPE_AGENT);
          ok = ok && (v >= target);
        }
        if (__all(ok)) break;
        if (++guard > (1 << 22)) break;  // deadlock escape (never in practice)
        __builtin_amdgcn_s_sleep(1);
      }
    }
    __builtin_amdgcn_fence(__ATOMIC_ACQUIRE, "workgroup");  // compiler fence
    __syncthreads();
  }

  // ---- readout: outputs[b][o] = states[b][T-1][:] . Wout[o][:]
  if (blk == 0) {
#pragma unroll 1
    for (int pi = 0; pi < 12; ++pi) {
      const int p = wv * 12 + pi;      // 8 waves x 12 = 96 pairs
      const int b = p / 3, o = p % 3;
      const float* sp = &states[((size_t)b * T_DIM + (T_DIM - 1)) * R_DIM];
      const float* wq = &Wout[(size_t)o * R_DIM];
      float a = 0.f;
#pragma unroll
      for (int j = 0; j < 8; ++j) {
        const int rr = j * 256 + lane * 4;
        const float4 s = *(const float4*)&sp[rr];
        const float4 w = *(const float4*)&wq[rr];
        a += s.x * w.x + s.y * w.y + s.z * w.z + s.w * w.w;
      }
#pragma unroll
      for (int m = 32; m >= 1; m >>= 1) a += __shfl_xor(a, m, 64);
      if (lane == 0) out[(size_t)b * O_DIM + o] = a;
    }
  }
}

extern "C" void kernel_launch(void* const* d_in, const int* in_sizes, int n_in,
                              void* d_out, int out_size, void* d_ws, size_t ws_size,
                              hipStream_t stream) {
  const float* x     = (const float*)d_in[0];
  const float* Win   = (const float*)d_in[1];
  const float* Wres  = (const float*)d_in[2];
  const float* Wout  = (const float*)d_in[3];
  const float* noise = (const float*)d_in[4];

  float* out    = (float*)d_out;              // [32,3]
  float* states = out + B_DIM * O_DIM;        // [32,1000,2048]
  int* flags    = (int*)d_ws;                 // [512], poison 0xAA < 1 (signed)

  esn_persist<<<NBLK, NTHR, 0, stream>>>(x, Win, Wres, Wout, noise,
                                         states, out, flags);
}

// Round 10
// 31217.200 us; speedup vs baseline: 3.2961x; 3.2961x over previous
//
#include <hip/hip_runtime.h>
#include <cstddef>

#define B_DIM 32
#define T_DIM 1000
#define I_DIM 3
#define R_DIM 2048
#define O_DIM 3
#define NBLK 256
#define ROWS 8          // reservoir rows per block
#define NTHR 512        // 8 waves: waves 0-3 = k-half 0, waves 4-7 = k-half 1
#define KCH 128         // k per chunk (lane*2 within chunk)
#define NCH 8           // chunks per half (8*128 = 1024)

// Persistent kernel, round 10: producer-consumer dataflow, NO grid barrier.
// states is a trajectory (step t writes [:,t,:], reads [:,t-1,:]) -> steps
// never overwrite each other -> the only ordering needed is per-chunk:
// chunk c of half h (k = h*1024+c*128..+127 = rows -> producer blocks
// h*128+16c..+15) must have flagged step t-1. Each block starts at its OWN
// chunk (rot = (blk>>4)&7; its flag + neighbors' set ~simultaneously) and
// waits with ONE 64-lane agent load per 4 chunks (2 waits/step, 2nd placed
// after 2 chunks of compute). Fast blocks stream ahead; barrier skew and
// first-touch LLC latency overlap with compute.
// Compute core + (512,2) envelope identical to round 7 (proven 128 VGPR,
// spill-free; rounds 8/9 proved tighter budgets -> allocator demotes acc[]
// to scratch = 5-7x regression).
__global__ __launch_bounds__(NTHR, 2) void esn_persist(
    const float* __restrict__ x,      // [B][T][I]
    const float* __restrict__ Win,    // [R][I]
    const float* __restrict__ Wres,   // [R][R]
    const float* __restrict__ Wout,   // [O][R]
    const float* __restrict__ noise,  // [B][R]
    float* __restrict__ states,       // [B][T][R]
    float* __restrict__ out,          // [B][O]
    int* __restrict__ flags)          // [NBLK] in ws (poison 0xAA = negative)
{
  __shared__ float cross[4][64];      // k-half combine (1 KB)

  const int tid   = threadIdx.x;
  const int blk   = blockIdx.x;
  const int r0    = blk * ROWS;
  const int h     = tid >> 8;         // k-half 0/1
  const int wv    = tid >> 6;         // wave 0..7
  const int wv4   = wv & 3;           // batch-group
  const int lane  = tid & 63;
  const int bbase = wv4 * 8;

  // chunk rotation: start at own chunk (works for both halves: (blk>>4)&7
  // == ((blk-128)>>4)&7 for blk>=128)
  const int rot = (blk >> 4) & 7;

  // output mapping: lane L -> (batch = bbase + (L>>3), row = r0 + (L&7))
  const int ob  = bbase + (lane >> 3);
  const int orr = r0 + (lane & 7);

  // t-invariant ext-term pieces (h==0 lanes produce outputs)
  float w0 = 0.f, w1 = 0.f, w2 = 0.f, nz = 0.f;
  if (h == 0) {
    w0 = Win[orr * I_DIM + 0];
    w1 = Win[orr * I_DIM + 1];
    w2 = Win[orr * I_DIM + 2];
    nz = noise[(size_t)ob * R_DIM + orr];
  }

  // waitf lane mapping (4 chunks per call): lane l checks chunk
  // (cbase + (l>>4)) & 7, producer (l&15) of this half.
  const int wf_coff = lane >> 4;      // 0..3
  const int wf_p    = lane & 15;

  // per-lane k base within this half; per-row/batch base pointers
  const int klb = h * 1024 + lane * 2;
  const float* wp[8];
  const float* sp0[8];
#pragma unroll
  for (int r = 0; r < 8; ++r) wp[r] = Wres + (size_t)(r0 + r) * R_DIM + klb;
#pragma unroll
  for (int j = 0; j < 8; ++j)
    sp0[j] = states + (size_t)(bbase + j) * T_DIM * R_DIM + klb;

#define LOADC(kc, SF, WF)                                                      \
  {                                                                            \
    _Pragma("unroll")                                                          \
    for (int j = 0; j < 8; ++j)                                                \
      SF[j] = *(const float2*)(sp0[j] + soff + (kc) * KCH);                    \
    _Pragma("unroll")                                                          \
    for (int r = 0; r < 8; ++r)                                                \
      WF[r] = *(const float2*)(wp[r] + (kc) * KCH);                            \
  }

#define FMAC(SF, WF)                                                           \
  {                                                                            \
    _Pragma("unroll")                                                          \
    for (int j = 0; j < 8; ++j) {                                              \
      _Pragma("unroll")                                                        \
      for (int r = 0; r < 8; ++r)                                              \
        acc[j * 8 + r] += WF[r].x * SF[j].x + WF[r].y * SF[j].y;               \
    }                                                                          \
  }

#define WAITF(cbase, target)                                                   \
  {                                                                            \
    const int c    = ((cbase) + wf_coff) & 7;                                  \
    const int pidx = h * 128 + c * 16 + wf_p;                                  \
    int guard = 0;                                                             \
    for (;;) {                                                                 \
      const int v = __hip_atomic_load(&flags[pidx], __ATOMIC_RELAXED,          \
                                      __HIP_MEMORY_SCOPE_AGENT);               \
      if (__all(v >= (target))) break;                                         \
      if (++guard > (1 << 22)) break; /* deadlock escape */                    \
      __builtin_amdgcn_s_sleep(1);                                             \
    }                                                                          \
    __builtin_amdgcn_fence(__ATOMIC_ACQUIRE, "workgroup");                     \
  }

#pragma unroll 1
  for (int t = 0; t < T_DIM; ++t) {
    // per-step input loads issued early (latency hides under the k-loop)
    float x0 = 0.f, x1 = 0.f, x2 = 0.f;
    if (h == 0) {
      const float* xp = &x[((size_t)ob * T_DIM + t) * I_DIM];
      x0 = xp[0]; x1 = xp[1]; x2 = xp[2];
    }

    float acc[64];
#pragma unroll
    for (int i = 0; i < 64; ++i) acc[i] = 0.f;

    if (t > 0) {
      const size_t soff = (size_t)(t - 1) * R_DIM;
      const int c0 = rot, c1 = (rot + 1) & 7, c2 = (rot + 2) & 7,
                c3 = (rot + 3) & 7, c4 = (rot + 4) & 7, c5 = (rot + 5) & 7,
                c6 = (rot + 6) & 7, c7 = (rot + 7) & 7;
      float2 sA[8], wA[8], sB[8], wB[8];
      WAITF(rot, t);                        // chunks c0..c3 ready
      LOADC(c0, sA, wA);
      LOADC(c1, sB, wB);
      FMAC(sA, wA); LOADC(c2, sA, wA);
      FMAC(sB, wB); LOADC(c3, sB, wB);
      WAITF(rot + 4, t);                    // chunks c4..c7 ready
      FMAC(sA, wA); LOADC(c4, sA, wA);
      FMAC(sB, wB); LOADC(c5, sB, wB);
      FMAC(sA, wA); LOADC(c6, sA, wA);
      FMAC(sB, wB); LOADC(c7, sB, wB);
      FMAC(sA, wA);
      FMAC(sB, wB);
    }

    // ---- in-place keep-half butterfly: acc[0] = lane L's output L partial
#pragma unroll
    for (int m = 32; m >= 1; m >>= 1) {
#pragma unroll
      for (int i = 0; i < m; ++i) {
        const bool hh = (lane & m) != 0;
        const float mine = hh ? acc[i] : acc[i + m];
        const float keep = hh ? acc[i + m] : acc[i];
        acc[i] = keep + __shfl_xor(mine, m, 64);
      }
    }

    // ---- combine k-halves, activation, sc1 store (LLC-visible)
    if (h == 1) cross[wv4][lane] = acc[0];
    __syncthreads();
    if (h == 0) {
      const float val =
          tanhf(x0 * w0 + x1 * w1 + x2 * w2 + nz + acc[0] + cross[wv4][lane]);
      __hip_atomic_store(&states[((size_t)ob * T_DIM + t) * R_DIM + orr], val,
                         __ATOMIC_RELAXED, __HIP_MEMORY_SCOPE_AGENT);
    }
    // syncthreads drains every wave's vmcnt -> all sc1 state stores retired
    // at LLC before tid0 releases the flag (also WAR-protects cross[]).
    __syncthreads();
    if (tid == 0)
      __hip_atomic_store(&flags[blk], t + 1, __ATOMIC_RELAXED,
                         __HIP_MEMORY_SCOPE_AGENT);
    // no grid barrier: next step's WAITF provides exactly the needed order
  }

  // ---- readout (block 0): wait everyone finished step T-1, then dot
  if (blk == 0) {
    if (wv == 0) {
      int guard = 0;
      for (;;) {
        bool ok = true;
#pragma unroll
        for (int j = 0; j < NBLK / 64; ++j) {
          const int v = __hip_atomic_load(&flags[lane + j * 64],
                                          __ATOMIC_RELAXED,
                                          __HIP_MEMORY_SCOPE_AGENT);
          ok = ok && (v >= T_DIM);
        }
        if (__all(ok)) break;
        if (++guard > (1 << 22)) break;
        __builtin_amdgcn_s_sleep(1);
      }
    }
    __builtin_amdgcn_fence(__ATOMIC_ACQUIRE, "workgroup");
    __syncthreads();
#pragma unroll 1
    for (int pi = 0; pi < 12; ++pi) {
      const int p = wv * 12 + pi;      // 8 waves x 12 = 96 pairs
      const int b = p / 3, o = p % 3;
      const float* sp = &states[((size_t)b * T_DIM + (T_DIM - 1)) * R_DIM];
      const float* wq = &Wout[(size_t)o * R_DIM];
      float a = 0.f;
#pragma unroll
      for (int j = 0; j < 8; ++j) {
        const int rr = j * 256 + lane * 4;
        const float4 s = *(const float4*)&sp[rr];
        const float4 w = *(const float4*)&wq[rr];
        a += s.x * w.x + s.y * w.y + s.z * w.z + s.w * w.w;
      }
#pragma unroll
      for (int m = 32; m >= 1; m >>= 1) a += __shfl_xor(a, m, 64);
      if (lane == 0) out[(size_t)b * O_DIM + o] = a;
    }
  }
}

extern "C" void kernel_launch(void* const* d_in, const int* in_sizes, int n_in,
                              void* d_out, int out_size, void* d_ws, size_t ws_size,
                              hipStream_t stream) {
  const float* x     = (const float*)d_in[0];
  const float* Win   = (const float*)d_in[1];
  const float* Wres  = (const float*)d_in[2];
  const float* Wout  = (const float*)d_in[3];
  const float* noise = (const float*)d_in[4];

  float* out    = (float*)d_out;              // [32,3]
  float* states = out + B_DIM * O_DIM;        // [32,1000,2048]
  int* flags    = (int*)d_ws;                 // [256], poison 0xAA < 1 (signed)

  esn_persist<<<NBLK, NTHR, 0, stream>>>(x, Win, Wres, Wout, noise,
                                         states, out, flags);
}